// Round 6
// baseline (141.018 us; speedup 1.0000x reference)
//
#include <hip/hip_runtime.h>
#include <hip/hip_cooperative_groups.h>

namespace cg = cooperative_groups;

// B=32, T=4096, D=512, R=64, LOCAL_SIZE=20, SAMPLING_RATE=10, LN_EPS=1e-5
static constexpr int Bsz   = 32;
static constexpr int Tlen  = 4096;
static constexpr int Ddim  = 512;
static constexpr int NSAMP = 408;   // len(range(0, 4076, 10))
static constexpr int NPRES = 20;
static constexpr int NROWS = NSAMP + NPRES;  // 428
static constexpr int RPB   = 64;    // rows per phase-A block
static constexpr int NBLK  = 7;     // ceil(428/64)
static constexpr int GRID  = 256;   // cooperative: 1 block/CU exactly
static constexpr int NTASK = Bsz * NPRES;    // 640 (b,l) expand tasks

typedef __attribute__((ext_vector_type(8))) short short8;  // 8 bf16
typedef __attribute__((ext_vector_type(4))) float f32x4;

__device__ __forceinline__ unsigned short f2bf(float x) {
  union { float f; unsigned u; } c; c.f = x;
  unsigned r = c.u + 0x7FFFu + ((c.u >> 16) & 1u);   // RNE
  return (unsigned short)(r >> 16);
}

// XOR-swizzle for row-major [64][512] bf16 tiles (1024 B rows); applied on
// both LDS write and read (reg-staged). Breaks the 16-rows-same-col bank
// conflict down to 2-way (free).
__device__ __forceinline__ int swz(int row, int colByte) {
  return (row << 10) + (colByte ^ ((row & 7) << 4));
}

__global__ __launch_bounds__(1024, 4) void fused_kernel(
    const float* __restrict__ obs, const float* __restrict__ wred,
    const float* __restrict__ bred, const float* __restrict__ gred,
    const float* __restrict__ betared,
    const float* __restrict__ wexp, const float* __restrict__ bexp,
    const float* __restrict__ gexp, const float* __restrict__ betaexp,
    float* __restrict__ bpart,     // ws [B][NBLK][64]
    float* __restrict__ present,   // ws [B][20][64]
    float* __restrict__ out_gm,    // [B][20][512]
    float* __restrict__ out_now)   // [B][64]
{
  __shared__ short xs[RPB * Ddim];     // 64 KB bf16, swizzled [row][k]
  __shared__ short wt[64 * Ddim];      // 64 KB bf16, swizzled [ch][k]
  __shared__ float sred[64][4];
  __shared__ float s2red[64][4];
  __shared__ float wmax[4][64];
  // phase B
  __shared__ float gmv[64];
  __shared__ float2 pacc[4][256];      // 8 KB partial sums
  __shared__ float redn[2][4];
  __shared__ float bc2[2];

  const int blk = blockIdx.x;
  const int tid = threadIdx.x;

  // ================= phase A: cf rows (224 blocks) =================
  if (blk < NBLK * Bsz) {
    const int b    = blk / NBLK;
    const int bx   = blk % NBLK;
    const int base = bx * RPB;
    char* xsB = (char*)xs;
    char* wtB = (char*)wt;

    // stage obs rows: f32 -> bf16 (coalesced float4 reads)
    const float* obs_b = obs + (size_t)b * Tlen * Ddim;
#pragma unroll
    for (int it = 0; it < 8; ++it) {
      int u    = it * 1024 + tid;       // 64 rows * 128 float4
      int row  = u >> 7;
      int c4   = u & 127;
      int graw = base + row;
      int gr   = graw < NROWS ? graw : NROWS - 1;   // clamp: benign dup
      int t    = gr < NSAMP ? gr * 10 : (Tlen - NPRES) + (gr - NSAMP);
      float4 v = *(const float4*)(obs_b + (size_t)t * Ddim + c4 * 4);
      uint2 wv;
      wv.x = (unsigned)f2bf(v.x) | ((unsigned)f2bf(v.y) << 16);
      wv.y = (unsigned)f2bf(v.z) | ((unsigned)f2bf(v.w) << 16);
      *(uint2*)(xsB + swz(row, c4 * 8)) = wv;
    }

    // stage w_red^T: wred[512][64] f32 -> wt[ch][k] bf16 (transpose)
#pragma unroll
    for (int it = 0; it < 4; ++it) {
      int dp = it * 64 + (tid >> 4);    // k-pair 0..255
      int d  = dp * 2;
      int r0 = (tid & 15) * 4;
      float4 va = *(const float4*)(wred + (size_t)d * 64 + r0);
      float4 vb = *(const float4*)(wred + (size_t)(d + 1) * 64 + r0);
      *(unsigned*)(wtB + swz(r0 + 0, d * 2)) =
          (unsigned)f2bf(va.x) | ((unsigned)f2bf(vb.x) << 16);
      *(unsigned*)(wtB + swz(r0 + 1, d * 2)) =
          (unsigned)f2bf(va.y) | ((unsigned)f2bf(vb.y) << 16);
      *(unsigned*)(wtB + swz(r0 + 2, d * 2)) =
          (unsigned)f2bf(va.z) | ((unsigned)f2bf(vb.z) << 16);
      *(unsigned*)(wtB + swz(r0 + 3, d * 2)) =
          (unsigned)f2bf(va.w) | ((unsigned)f2bf(vb.w) << 16);
    }
    __syncthreads();

    // MFMA: wave w -> row-group w&3, ch-group w>>2
    const int w    = tid >> 6;
    const int lane = tid & 63;
    const int l15  = lane & 15;
    const int lhi  = lane >> 4;
    const int rowg = w & 3;
    const int chg  = w >> 2;
    const int arow = rowg * 16 + l15;
    const int brow = chg * 16 + l15;

    f32x4 acc = {0.f, 0.f, 0.f, 0.f};
#pragma unroll
    for (int ks = 0; ks < 16; ++ks) {
      int colB = ks * 64 + lhi * 16;
      short8 av = *(const short8*)(xsB + swz(arow, colB));
      short8 bv = *(const short8*)(wtB + swz(brow, colB));
      acc = __builtin_amdgcn_mfma_f32_16x16x32_bf16(av, bv, acc, 0, 0, 0);
    }

    // epilogue: bias+ReLU, cross-wave LN (ch = lane&15, row = lhi*4+q)
    const int c  = chg * 16 + l15;
    const float bb = bred[c], gg = gred[c], be = betared[c];
    float y[4];
#pragma unroll
    for (int q = 0; q < 4; ++q) {
      y[q] = fmaxf(acc[q] + bb, 0.f);
      float s = y[q], s2 = y[q] * y[q];
#pragma unroll
      for (int msk = 1; msk <= 8; msk <<= 1) {
        s  += __shfl_xor(s,  msk, 64);
        s2 += __shfl_xor(s2, msk, 64);
      }
      if (l15 == 0) {
        int grow = rowg * 16 + lhi * 4 + q;
        sred[grow][chg]  = s;
        s2red[grow][chg] = s2;
      }
    }
    __syncthreads();

    float m = -INFINITY;
    float* pres_b = present + (size_t)b * NPRES * 64;
#pragma unroll
    for (int q = 0; q < 4; ++q) {
      int grow = rowg * 16 + lhi * 4 + q;
      float S  = sred[grow][0] + sred[grow][1] + sred[grow][2] + sred[grow][3];
      float S2 = s2red[grow][0] + s2red[grow][1] + s2red[grow][2] + s2red[grow][3];
      float mean = S * (1.f / 64.f);
      float var  = S2 * (1.f / 64.f) - mean * mean;
      float inv  = rsqrtf(fmaxf(var, 0.f) + 1e-5f);
      float cf   = (y[q] - mean) * inv * gg + be;
      int graw = base + grow;
      int gr   = graw < NROWS ? graw : NROWS - 1;
      if (gr < NSAMP) {
        m = fmaxf(m, cf);
      } else {
        int l = gr - NSAMP;
        pres_b[l * 64 + c] = cf;
        if (gr == NROWS - 1) out_now[b * 64 + c] = cf;
      }
    }

    m = fmaxf(m, __shfl_xor(m, 16, 64));
    m = fmaxf(m, __shfl_xor(m, 32, 64));
    if (lhi == 0) wmax[rowg][c] = m;
    __syncthreads();
    if (tid < 64) {
      float mm = fmaxf(fmaxf(wmax[0][tid], wmax[1][tid]),
                       fmaxf(wmax[2][tid], wmax[3][tid]));
      bpart[((size_t)b * NBLK + bx) * 64 + tid] = mm;
    }
  }

  // Writer-side flush (L2 -> coherence point) so other XCDs see
  // bpart/present after the grid barrier.
  __threadfence();
  cg::this_grid().sync();

  // ================= phase B: expand (all 256 blocks) =================
  const int q  = tid >> 8;        // 0..3: K-split over R
  const int dp = tid & 255;       // d-pair: d = 2*dp, 2*dp+1
  for (int t = blk; t < NTASK; t += GRID) {
    const int b = t / NPRES;
    const int l = t % NPRES;

    if (tid < 64) {
      float v = bpart[(size_t)b * NBLK * 64 + tid];
      for (int s = 1; s < NBLK; ++s)
        v = fmaxf(v, bpart[((size_t)b * NBLK + s) * 64 + tid]);
      for (int j = 0; j <= l; ++j)
        v = fmaxf(v, present[((size_t)b * NPRES + j) * 64 + tid]);
      gmv[tid] = v;
    }
    __syncthreads();

    float a0 = 0.f, a1 = 0.f;
#pragma unroll
    for (int i = 0; i < 16; ++i) {
      int r = q * 16 + i;
      float g  = gmv[r];
      float2 wv = *(const float2*)(wexp + (size_t)r * Ddim + 2 * dp);
      a0 = fmaf(g, wv.x, a0);
      a1 = fmaf(g, wv.y, a1);
    }
    pacc[q][dp] = make_float2(a0, a1);
    __syncthreads();

    float y0 = 0.f, y1 = 0.f;
    if (tid < 256) {
      float2 p0 = pacc[0][dp], p1 = pacc[1][dp];
      float2 p2 = pacc[2][dp], p3 = pacc[3][dp];
      float2 bb = *(const float2*)(bexp + 2 * dp);
      y0 = fmaxf(p0.x + p1.x + p2.x + p3.x + bb.x, 0.f);
      y1 = fmaxf(p0.y + p1.y + p2.y + p3.y + bb.y, 0.f);
      float s = y0 + y1, s2 = fmaf(y0, y0, y1 * y1);
#pragma unroll
      for (int msk = 32; msk >= 1; msk >>= 1) {
        s  += __shfl_xor(s,  msk, 64);
        s2 += __shfl_xor(s2, msk, 64);
      }
      if ((tid & 63) == 0) { redn[0][tid >> 6] = s; redn[1][tid >> 6] = s2; }
    }
    __syncthreads();
    if (tid == 0) {
      float S  = redn[0][0] + redn[0][1] + redn[0][2] + redn[0][3];
      float S2 = redn[1][0] + redn[1][1] + redn[1][2] + redn[1][3];
      float mean = S * (1.f / 512.f);
      float var  = S2 * (1.f / 512.f) - mean * mean;
      bc2[0] = mean;
      bc2[1] = rsqrtf(fmaxf(var, 0.f) + 1e-5f);
    }
    __syncthreads();
    if (tid < 256) {
      float2 gg = *(const float2*)(gexp + 2 * dp);
      float2 be = *(const float2*)(betaexp + 2 * dp);
      float mean = bc2[0], inv = bc2[1];
      size_t o = ((size_t)b * NPRES + l) * Ddim + 2 * dp;
      out_gm[o]     = (y0 - mean) * inv * gg.x + be.x;
      out_gm[o + 1] = (y1 - mean) * inv * gg.y + be.y;
    }
    __syncthreads();   // protect gmv/pacc reuse next task
  }
}

extern "C" void kernel_launch(void* const* d_in, const int* in_sizes, int n_in,
                              void* d_out, int out_size, void* d_ws, size_t ws_size,
                              hipStream_t stream) {
  const float* obs     = (const float*)d_in[0];
  const float* wred    = (const float*)d_in[1];
  const float* bred    = (const float*)d_in[2];
  const float* gred    = (const float*)d_in[3];
  const float* betared = (const float*)d_in[4];
  const float* wexp    = (const float*)d_in[5];
  const float* bexp    = (const float*)d_in[6];
  const float* gexp    = (const float*)d_in[7];
  const float* betaexp = (const float*)d_in[8];

  float* out_gm  = (float*)d_out;                       // 32*20*512
  float* out_now = (float*)d_out + Bsz * NPRES * Ddim;  // 32*64

  float* bpart   = (float*)d_ws;                        // 32*7*64
  float* present = bpart + Bsz * NBLK * 64;             // 32*20*64

  void* args[] = {
    (void*)&obs, (void*)&wred, (void*)&bred, (void*)&gred, (void*)&betared,
    (void*)&wexp, (void*)&bexp, (void*)&gexp, (void*)&betaexp,
    (void*)&bpart, (void*)&present, (void*)&out_gm, (void*)&out_now,
  };
  hipLaunchCooperativeKernel((const void*)fused_kernel, dim3(GRID), dim3(1024),
                             args, 0, stream);
}

// Round 7
// 30.412 us; speedup vs baseline: 4.6369x; 4.6369x over previous
//
#include <hip/hip_runtime.h>

// B=32, T=4096, D=512, R=64, LOCAL_SIZE=20, SAMPLING_RATE=10, LN_EPS=1e-5
static constexpr int Bsz   = 32;
static constexpr int Tlen  = 4096;
static constexpr int Ddim  = 512;
static constexpr int NSAMP = 408;   // len(range(0, 4076, 10))
static constexpr int NPRES = 20;
static constexpr int NROWS = NSAMP + NPRES;  // 428
static constexpr int RPB   = 64;    // rows per k1 block
static constexpr int NBLK  = 7;     // ceil(428/64)

typedef __attribute__((ext_vector_type(8))) short short8;  // 8 bf16
typedef __attribute__((ext_vector_type(4))) float f32x4;

__device__ __forceinline__ unsigned short f2bf(float x) {
  union { float f; unsigned u; } c; c.f = x;
  unsigned r = c.u + 0x7FFFu + ((c.u >> 16) & 1u);   // RNE
  return (unsigned short)(r >> 16);
}

// XOR-swizzle for the row-major [64][512] bf16 obs tile (1024 B rows):
// breaks the 16-rows-same-col bank conflict to 2-way (free). Applied on
// both LDS write and read (reg-staged staging, so legal).
__device__ __forceinline__ int swz(int row, int colByte) {
  return (row << 10) + (colByte ^ ((row & 7) << 4));
}

// K0: pre-pack w_red^T as bf16 [64 ch][512 k] into workspace (done once per
// call; K1 reads B-fragments from it via L1/L2 instead of re-transposing
// per block). Reads coalesced (lanes span ch at fixed k).
__global__ __launch_bounds__(256) void k0_pack(
    const float* __restrict__ wred, unsigned short* __restrict__ wt_g)
{
  int t  = blockIdx.x * 256 + threadIdx.x;   // 0..16383
  int kg = t >> 6;                           // 0..255 (k-pair)
  int ch = t & 63;
  int k0 = kg * 2;
  float a = wred[(size_t)k0 * 64 + ch];
  float b = wred[(size_t)(k0 + 1) * 64 + ch];
  unsigned pack = (unsigned)f2bf(a) | ((unsigned)f2bf(b) << 16);
  *(unsigned*)(wt_g + (size_t)ch * Ddim + k0) = pack;
}

// K1: cf = LN(ReLU(obs_rows @ w_red + b_red)) for the 428 needed rows.
// 1024 threads = 16 waves: wave w owns rows (w&3)*16..+15 and chs
// (w>>2)*16..+15. A-fragments from swizzled LDS; B-fragments from the
// pre-packed global wt (L1-resident, 16 KB per ch-group). LDS = 67 KB ->
// 2 blocks/CU; launch_bounds(,8) caps VGPR at 64 so occupancy is real.
__global__ __launch_bounds__(1024, 8) void k1_cf(
    const float* __restrict__ obs, const unsigned short* __restrict__ wt_g,
    const float* __restrict__ bred, const float* __restrict__ gred,
    const float* __restrict__ betared,
    float* __restrict__ bpart,     // [B][NBLK][64]
    float* __restrict__ present,   // [B][20][64]
    float* __restrict__ out_now)   // [B][64]
{
  __shared__ short xs[RPB * Ddim];     // 64 KB bf16, swizzled [row][k]
  __shared__ float sred[64][4];        // per-row, per-ch-group partials
  __shared__ float s2red[64][4];
  __shared__ float wmax[4][64];

  const int b    = blockIdx.y;
  const int bx   = blockIdx.x;
  const int base = bx * RPB;
  const int tid  = threadIdx.x;
  char* xsB = (char*)xs;

  // ---- stage obs rows: f32 -> bf16 into xs (coalesced float4 reads) ----
  const float* obs_b = obs + (size_t)b * Tlen * Ddim;
#pragma unroll
  for (int it = 0; it < 8; ++it) {
    int u    = it * 1024 + tid;       // 0..8191 = 64 rows * 128 float4
    int row  = u >> 7;
    int c4   = u & 127;
    int graw = base + row;
    int gr   = graw < NROWS ? graw : NROWS - 1;   // clamp: benign dup work
    int t    = gr < NSAMP ? gr * 10 : (Tlen - NPRES) + (gr - NSAMP);
    float4 v = *(const float4*)(obs_b + (size_t)t * Ddim + c4 * 4);
    uint2 wv;
    wv.x = (unsigned)f2bf(v.x) | ((unsigned)f2bf(v.y) << 16);
    wv.y = (unsigned)f2bf(v.z) | ((unsigned)f2bf(v.w) << 16);
    *(uint2*)(xsB + swz(row, c4 * 8)) = wv;
  }
  __syncthreads();

  // ---- MFMA: wave w -> row-group w&3, ch-group w>>2 ----
  const int w    = tid >> 6;
  const int lane = tid & 63;
  const int l15  = lane & 15;
  const int lhi  = lane >> 4;
  const int rowg = w & 3;
  const int chg  = w >> 2;
  const int arow = rowg * 16 + l15;
  const int brow = chg * 16 + l15;
  const char* wrow = (const char*)(wt_g + (size_t)brow * Ddim);

  f32x4 acc = {0.f, 0.f, 0.f, 0.f};
#pragma unroll
  for (int ks = 0; ks < 16; ++ks) {
    int colB = ks * 64 + lhi * 16;    // byte offset of this lane's k-window
    short8 av = *(const short8*)(xsB + swz(arow, colB));
    short8 bv = *(const short8*)(wrow + colB);
    acc = __builtin_amdgcn_mfma_f32_16x16x32_bf16(av, bv, acc, 0, 0, 0);
  }

  // ---- epilogue: bias+ReLU, cross-wave LN (ch = lane&15, row = lhi*4+q) --
  const int c  = chg * 16 + l15;
  const float bb = bred[c], gg = gred[c], be = betared[c];
  float y[4];
#pragma unroll
  for (int q = 0; q < 4; ++q) {
    y[q] = fmaxf(acc[q] + bb, 0.f);
    float s = y[q], s2 = y[q] * y[q];
#pragma unroll
    for (int msk = 1; msk <= 8; msk <<= 1) {
      s  += __shfl_xor(s,  msk, 64);
      s2 += __shfl_xor(s2, msk, 64);
    }
    if (l15 == 0) {
      int grow = rowg * 16 + lhi * 4 + q;
      sred[grow][chg]  = s;
      s2red[grow][chg] = s2;
    }
  }
  __syncthreads();

  float m = -INFINITY;
  float* pres_b = present + (size_t)b * NPRES * 64;
#pragma unroll
  for (int q = 0; q < 4; ++q) {
    int grow = rowg * 16 + lhi * 4 + q;
    float S  = sred[grow][0] + sred[grow][1] + sred[grow][2] + sred[grow][3];
    float S2 = s2red[grow][0] + s2red[grow][1] + s2red[grow][2] + s2red[grow][3];
    float mean = S * (1.f / 64.f);
    float var  = S2 * (1.f / 64.f) - mean * mean;
    float inv  = rsqrtf(fmaxf(var, 0.f) + 1e-5f);
    float cf   = (y[q] - mean) * inv * gg + be;
    int graw = base + grow;
    int gr   = graw < NROWS ? graw : NROWS - 1;
    if (gr < NSAMP) {
      m = fmaxf(m, cf);
    } else {
      int l = gr - NSAMP;
      pres_b[l * 64 + c] = cf;
      if (gr == NROWS - 1) out_now[b * 64 + c] = cf;
    }
  }

  // block-level sampled max -> bpart (no atomics; deterministic)
  m = fmaxf(m, __shfl_xor(m, 16, 64));
  m = fmaxf(m, __shfl_xor(m, 32, 64));
  if (lhi == 0) wmax[rowg][c] = m;
  __syncthreads();
  if (tid < 64) {
    float mm = fmaxf(fmaxf(wmax[0][tid], wmax[1][tid]),
                     fmaxf(wmax[2][tid], wmax[3][tid]));
    bpart[((size_t)b * NBLK + bx) * 64 + tid] = mm;
  }
}

// K3: one block per (b,l) task (640 blocks -> makespan 3 tasks/CU, vs 4
// with the 2-task/320-block shape). 4-wave-parallel prefix-max, then
// out = LN(ReLU(gm @ w_exp + b_exp)) over D=512.
__global__ __launch_bounds__(256, 8) void k3_expand(
    const float* __restrict__ wexp, const float* __restrict__ bexp,
    const float* __restrict__ gexp, const float* __restrict__ betaexp,
    const float* __restrict__ bpart, const float* __restrict__ present,
    float* __restrict__ out_gm)      // [B][20][512]
{
  __shared__ float part[4][64];
  __shared__ float gm[64];
  __shared__ float red_s[4], red_s2[4];
  __shared__ float bc[2];
  const int l = blockIdx.x;   // 0..19
  const int b = blockIdx.y;
  const int tid = threadIdx.x;
  const int r = tid & 63, j = tid >> 6;

  const int nsrc = NBLK + l + 1;     // 7 block-partials + l+1 present rows
  float v = -INFINITY;
  for (int s = j; s < nsrc; s += 4)
    v = fmaxf(v, s < NBLK ? bpart[((size_t)b * NBLK + s) * 64 + r]
                          : present[((size_t)b * NPRES + (s - NBLK)) * 64 + r]);
  part[j][r] = v;
  __syncthreads();
  if (tid < 64)
    gm[tid] = fmaxf(fmaxf(part[0][tid], part[1][tid]),
                    fmaxf(part[2][tid], part[3][tid]));
  __syncthreads();

  const int d0 = tid, d1 = tid + 256;
  float a0 = 0.f, a1 = 0.f;
#pragma unroll 8
  for (int rr = 0; rr < 64; ++rr) {
    float g = gm[rr];
    a0 = fmaf(g, wexp[rr * Ddim + d0], a0);
    a1 = fmaf(g, wexp[rr * Ddim + d1], a1);
  }
  float y0 = fmaxf(a0 + bexp[d0], 0.f);
  float y1 = fmaxf(a1 + bexp[d1], 0.f);

  float s = y0 + y1, s2 = fmaf(y0, y0, y1 * y1);
#pragma unroll
  for (int m = 32; m >= 1; m >>= 1) {
    s  += __shfl_xor(s,  m, 64);
    s2 += __shfl_xor(s2, m, 64);
  }
  int wid = tid >> 6, lane = tid & 63;
  if (lane == 0) { red_s[wid] = s; red_s2[wid] = s2; }
  __syncthreads();
  if (tid == 0) {
    float S  = red_s[0] + red_s[1] + red_s[2] + red_s[3];
    float S2 = red_s2[0] + red_s2[1] + red_s2[2] + red_s2[3];
    float mean = S * (1.f / 512.f);
    float var  = S2 * (1.f / 512.f) - mean * mean;
    bc[0] = mean;
    bc[1] = rsqrtf(fmaxf(var, 0.f) + 1e-5f);
  }
  __syncthreads();
  float mean = bc[0], inv = bc[1];
  size_t o = ((size_t)b * NPRES + l) * Ddim;
  out_gm[o + d0] = (y0 - mean) * inv * gexp[d0] + betaexp[d0];
  out_gm[o + d1] = (y1 - mean) * inv * gexp[d1] + betaexp[d1];
}

extern "C" void kernel_launch(void* const* d_in, const int* in_sizes, int n_in,
                              void* d_out, int out_size, void* d_ws, size_t ws_size,
                              hipStream_t stream) {
  const float* obs     = (const float*)d_in[0];
  const float* wred    = (const float*)d_in[1];
  const float* bred    = (const float*)d_in[2];
  const float* gred    = (const float*)d_in[3];
  const float* betared = (const float*)d_in[4];
  const float* wexp    = (const float*)d_in[5];
  const float* bexp    = (const float*)d_in[6];
  const float* gexp    = (const float*)d_in[7];
  const float* betaexp = (const float*)d_in[8];

  float* out_gm  = (float*)d_out;                       // 32*20*512
  float* out_now = (float*)d_out + Bsz * NPRES * Ddim;  // 32*64

  unsigned short* wt_g = (unsigned short*)d_ws;         // 64*512 bf16 = 64 KB
  float* bpart   = (float*)((char*)d_ws + 64 * Ddim * sizeof(short));
  float* present = bpart + Bsz * NBLK * 64;             // 32*20*64

  k0_pack<<<64, 256, 0, stream>>>(wred, wt_g);

  dim3 g1(NBLK, Bsz);                // 7 x 32 = 224 blocks, 1024 thr
  k1_cf<<<g1, 1024, 0, stream>>>(obs, wt_g, bred, gred, betared,
                                 bpart, present, out_now);

  dim3 g3(NPRES, Bsz);               // 20 x 32 = 640 blocks
  k3_expand<<<g3, 256, 0, stream>>>(wexp, bexp, gexp, betaexp,
                                    bpart, present, out_gm);
}

// Round 8
// 22.506 us; speedup vs baseline: 6.2660x; 1.3513x over previous
//
#include <hip/hip_runtime.h>

// B=32, T=4096, D=512, R=64, LOCAL_SIZE=20, SAMPLING_RATE=10, LN_EPS=1e-5
static constexpr int Bsz   = 32;
static constexpr int Tlen  = 4096;
static constexpr int Ddim  = 512;
static constexpr int NSAMP = 408;   // len(range(0, 4076, 10))
static constexpr int NPRES = 20;
static constexpr int NROWS = NSAMP + NPRES;  // 428
static constexpr int RPB   = 64;    // rows per k1 block
static constexpr int NBLK  = 7;     // ceil(428/64)

typedef __attribute__((ext_vector_type(8))) short short8;  // 8 bf16
typedef __attribute__((ext_vector_type(4))) float f32x4;

// HW packed f32->bf16 (RNE). No builtin on gfx950; inline asm per guide T12.
__device__ __forceinline__ unsigned cvt_pk_bf16(float lo, float hi) {
  unsigned r;
  asm("v_cvt_pk_bf16_f32 %0, %1, %2" : "=v"(r) : "v"(lo), "v"(hi));
  return r;
}

// XOR-swizzle for row-major [64][512] bf16 tiles (1024 B rows): 16 lanes
// reading 16 rows at one col-window would all hit the same bank. XOR bits
// 4-6 of the col-byte with row&7 -> 8 distinct 16B slots -> 2-way (free).
// Applied on BOTH LDS write and read (reg-staged staging, so legal).
__device__ __forceinline__ int swz(int row, int colByte) {
  return (row << 10) + (colByte ^ ((row & 7) << 4));
}

// K1: cf = LN(ReLU(obs_rows @ w_red + b_red)) for the 428 needed rows.
// 1024 threads = 16 waves: wave w owns rows (w&3)*16..+15 and chs
// (w>>2)*16..+15 (one 16x16x32 MFMA chain). LN over 64 chs = in-wave
// 16-lane shuffle partial + 4-way cross-wave LDS reduce.
// NOTE (r7 lesson): keep BOTH MFMA operands in LDS; do not cap VGPRs.
__global__ __launch_bounds__(1024) void k1_cf(
    const float* __restrict__ obs, const float* __restrict__ wred,
    const float* __restrict__ bred, const float* __restrict__ gred,
    const float* __restrict__ betared,
    float* __restrict__ bpart,     // [B][NBLK][64]
    float* __restrict__ present,   // [B][20][64]
    float* __restrict__ out_now)   // [B][64]
{
  __shared__ short xs[RPB * Ddim];     // 64 KB bf16, swizzled [row][k]
  __shared__ short wt[64 * Ddim];      // 64 KB bf16, swizzled [ch][k]
  __shared__ float sred[64][4];        // per-row, per-ch-group sum partials
  __shared__ float s2red[64][4];
  __shared__ float wmax[4][64];        // per-row-group sampled max

  const int b    = blockIdx.y;
  const int bx   = blockIdx.x;
  const int base = bx * RPB;
  const int tid  = threadIdx.x;
  char* xsB = (char*)xs;
  char* wtB = (char*)wt;

  // ---- stage obs rows: f32 -> bf16 into xs (coalesced float4 reads) ----
  const float* obs_b = obs + (size_t)b * Tlen * Ddim;
#pragma unroll
  for (int it = 0; it < 8; ++it) {
    int u    = it * 1024 + tid;       // 0..8191 = 64 rows * 128 float4
    int row  = u >> 7;
    int c4   = u & 127;
    int graw = base + row;
    int gr   = graw < NROWS ? graw : NROWS - 1;   // clamp: benign dup work
    int t    = gr < NSAMP ? gr * 10 : (Tlen - NPRES) + (gr - NSAMP);
    float4 v = *(const float4*)(obs_b + (size_t)t * Ddim + c4 * 4);
    uint2 wv;
    wv.x = cvt_pk_bf16(v.x, v.y);
    wv.y = cvt_pk_bf16(v.z, v.w);
    *(uint2*)(xsB + swz(row, c4 * 8)) = wv;
  }

  // ---- stage w_red^T: wred[512][64] f32 -> wt[ch][k] bf16 (transpose) ----
#pragma unroll
  for (int it = 0; it < 4; ++it) {
    int dp = it * 64 + (tid >> 4);    // k-pair index 0..255
    int d  = dp * 2;
    int r0 = (tid & 15) * 4;
    float4 va = *(const float4*)(wred + (size_t)d * 64 + r0);
    float4 vb = *(const float4*)(wred + (size_t)(d + 1) * 64 + r0);
    *(unsigned*)(wtB + swz(r0 + 0, d * 2)) = cvt_pk_bf16(va.x, vb.x);
    *(unsigned*)(wtB + swz(r0 + 1, d * 2)) = cvt_pk_bf16(va.y, vb.y);
    *(unsigned*)(wtB + swz(r0 + 2, d * 2)) = cvt_pk_bf16(va.z, vb.z);
    *(unsigned*)(wtB + swz(r0 + 3, d * 2)) = cvt_pk_bf16(va.w, vb.w);
  }
  __syncthreads();

  // ---- MFMA: wave w -> row-group w&3, ch-group w>>2 ----
  const int w    = tid >> 6;
  const int lane = tid & 63;
  const int l15  = lane & 15;
  const int lhi  = lane >> 4;
  const int rowg = w & 3;
  const int chg  = w >> 2;
  const int arow = rowg * 16 + l15;
  const int brow = chg * 16 + l15;

  f32x4 acc = {0.f, 0.f, 0.f, 0.f};
#pragma unroll
  for (int ks = 0; ks < 16; ++ks) {
    int colB = ks * 64 + lhi * 16;    // byte offset of this lane's k-window
    short8 av = *(const short8*)(xsB + swz(arow, colB));
    short8 bv = *(const short8*)(wtB + swz(brow, colB));
    acc = __builtin_amdgcn_mfma_f32_16x16x32_bf16(av, bv, acc, 0, 0, 0);
  }

  // ---- epilogue: bias+ReLU, cross-wave LN ----
  // C/D layout (m89-verified): ch (B free dim) = lane&15, obs row (A free
  // dim) = (lane>>4)*4 + q.
  const int c  = chg * 16 + l15;
  const float bb = bred[c], gg = gred[c], be = betared[c];
  float y[4];
#pragma unroll
  for (int q = 0; q < 4; ++q) {
    y[q] = fmaxf(acc[q] + bb, 0.f);
    float s = y[q], s2 = y[q] * y[q];
#pragma unroll
    for (int msk = 1; msk <= 8; msk <<= 1) {
      s  += __shfl_xor(s,  msk, 64);
      s2 += __shfl_xor(s2, msk, 64);
    }
    if (l15 == 0) {
      int grow = rowg * 16 + lhi * 4 + q;
      sred[grow][chg]  = s;
      s2red[grow][chg] = s2;
    }
  }
  __syncthreads();

  float m = -INFINITY;
  float* pres_b = present + (size_t)b * NPRES * 64;
#pragma unroll
  for (int q = 0; q < 4; ++q) {
    int grow = rowg * 16 + lhi * 4 + q;
    float S  = sred[grow][0] + sred[grow][1] + sred[grow][2] + sred[grow][3];
    float S2 = s2red[grow][0] + s2red[grow][1] + s2red[grow][2] + s2red[grow][3];
    float mean = S * (1.f / 64.f);
    float var  = S2 * (1.f / 64.f) - mean * mean;
    float inv  = rsqrtf(fmaxf(var, 0.f) + 1e-5f);
    float cf   = (y[q] - mean) * inv * gg + be;
    int graw = base + grow;
    int gr   = graw < NROWS ? graw : NROWS - 1;
    if (gr < NSAMP) {
      m = fmaxf(m, cf);
    } else {
      int l = gr - NSAMP;
      pres_b[l * 64 + c] = cf;
      if (gr == NROWS - 1) out_now[b * 64 + c] = cf;
    }
  }

  // block-level sampled max -> bpart (no atomics; deterministic)
  m = fmaxf(m, __shfl_xor(m, 16, 64));
  m = fmaxf(m, __shfl_xor(m, 32, 64));
  if (lhi == 0) wmax[rowg][c] = m;
  __syncthreads();
  if (tid < 64) {
    float mm = fmaxf(fmaxf(wmax[0][tid], wmax[1][tid]),
                     fmaxf(wmax[2][tid], wmax[3][tid]));
    bpart[((size_t)b * NBLK + bx) * 64 + tid] = mm;
  }
}

// K3: one block per (b,l) task (640 blocks -> makespan 3 tasks/CU vs 4 for
// the 320x2 shape). 4-wave-parallel prefix-max, then
// out = LN(ReLU(gm @ w_exp + b_exp)) over D=512 (2 outputs per thread).
__global__ __launch_bounds__(256) void k3_expand(
    const float* __restrict__ wexp, const float* __restrict__ bexp,
    const float* __restrict__ gexp, const float* __restrict__ betaexp,
    const float* __restrict__ bpart, const float* __restrict__ present,
    float* __restrict__ out_gm)      // [B][20][512]
{
  __shared__ float part[4][64];
  __shared__ float gm[64];
  __shared__ float red_s[4], red_s2[4];
  __shared__ float bc[2];
  const int l = blockIdx.x;   // 0..19
  const int b = blockIdx.y;
  const int tid = threadIdx.x;
  const int r = tid & 63, j = tid >> 6;

  const int nsrc = NBLK + l + 1;     // 7 block-partials + l+1 present rows
  float v = -INFINITY;
  for (int s = j; s < nsrc; s += 4)
    v = fmaxf(v, s < NBLK ? bpart[((size_t)b * NBLK + s) * 64 + r]
                          : present[((size_t)b * NPRES + (s - NBLK)) * 64 + r]);
  part[j][r] = v;
  __syncthreads();
  if (tid < 64)
    gm[tid] = fmaxf(fmaxf(part[0][tid], part[1][tid]),
                    fmaxf(part[2][tid], part[3][tid]));
  __syncthreads();

  const int d0 = tid, d1 = tid + 256;
  float a0 = 0.f, a1 = 0.f;
#pragma unroll 8
  for (int rr = 0; rr < 64; ++rr) {
    float g = gm[rr];
    a0 = fmaf(g, wexp[rr * Ddim + d0], a0);
    a1 = fmaf(g, wexp[rr * Ddim + d1], a1);
  }
  float y0 = fmaxf(a0 + bexp[d0], 0.f);
  float y1 = fmaxf(a1 + bexp[d1], 0.f);

  float s = y0 + y1, s2 = fmaf(y0, y0, y1 * y1);
#pragma unroll
  for (int m = 32; m >= 1; m >>= 1) {
    s  += __shfl_xor(s,  m, 64);
    s2 += __shfl_xor(s2, m, 64);
  }
  int wid = tid >> 6, lane = tid & 63;
  if (lane == 0) { red_s[wid] = s; red_s2[wid] = s2; }
  __syncthreads();
  if (tid == 0) {
    float S  = red_s[0] + red_s[1] + red_s[2] + red_s[3];
    float S2 = red_s2[0] + red_s2[1] + red_s2[2] + red_s2[3];
    float mean = S * (1.f / 512.f);
    float var  = S2 * (1.f / 512.f) - mean * mean;
    bc[0] = mean;
    bc[1] = rsqrtf(fmaxf(var, 0.f) + 1e-5f);
  }
  __syncthreads();
  float mean = bc[0], inv = bc[1];
  size_t o = ((size_t)b * NPRES + l) * Ddim;
  out_gm[o + d0] = (y0 - mean) * inv * gexp[d0] + betaexp[d0];
  out_gm[o + d1] = (y1 - mean) * inv * gexp[d1] + betaexp[d1];
}

extern "C" void kernel_launch(void* const* d_in, const int* in_sizes, int n_in,
                              void* d_out, int out_size, void* d_ws, size_t ws_size,
                              hipStream_t stream) {
  const float* obs     = (const float*)d_in[0];
  const float* wred    = (const float*)d_in[1];
  const float* bred    = (const float*)d_in[2];
  const float* gred    = (const float*)d_in[3];
  const float* betared = (const float*)d_in[4];
  const float* wexp    = (const float*)d_in[5];
  const float* bexp    = (const float*)d_in[6];
  const float* gexp    = (const float*)d_in[7];
  const float* betaexp = (const float*)d_in[8];

  float* out_gm  = (float*)d_out;                       // 32*20*512
  float* out_now = (float*)d_out + Bsz * NPRES * Ddim;  // 32*64

  float* bpart   = (float*)d_ws;                        // 32*7*64
  float* present = bpart + Bsz * NBLK * 64;             // 32*20*64

  dim3 g1(NBLK, Bsz);                // 7 x 32 = 224 blocks, 1024 thr
  k1_cf<<<g1, 1024, 0, stream>>>(obs, wred, bred, gred, betared,
                                 bpart, present, out_now);

  dim3 g3(NPRES, Bsz);               // 20 x 32 = 640 blocks
  k3_expand<<<g3, 256, 0, stream>>>(wexp, bexp, gexp, betaexp,
                                    bpart, present, out_gm);
}